// Round 5
// baseline (50.955 us; speedup 1.0000x reference)
//
#include <hip/hip_runtime.h>
#include <math.h>

#define C_DIM 128
#define H_DIM 128
#define W_DIM 128
#define HW (H_DIM * W_DIM)
#define EPS_N 1e-12f
#define NT 512
#define NW 8            // waves per block
#define CPW 16          // channels per wave
#define NSLOT 4         // LDS reduce slots

// One block per image row. Wave w handles channels [w*16, w*16+16) for the
// whole 128-px row; lane l owns pixels (2l, 2l+1) via float2 loads; column
// neighbors come from cross-lane shuffles. fused-norms are computed in-pass.
__global__ __launch_bounds__(NT) void asfr_fused2(
    const float* __restrict__ fe,
    const float* __restrict__ fu,
    float* __restrict__ out)
{
    __shared__ float part [NSLOT][W_DIM][11];  // 9 dots + fe2, padded
    __shared__ float part2[NSLOT][3][W_DIM];   // fu norm^2 per (row_off, col)
    __shared__ float n2r  [3][W_DIM];          // reciprocal clamped norms
    __shared__ float wl   [W_DIM][11];         // softmax weights, padded

    const int tid = threadIdx.x;
    const int l   = tid & 63;
    const int wv  = tid >> 6;

    // XCD-chunked bijective swizzle (gridDim.x % 8 == 0): consecutive rows
    // land on the same XCD so fu row re-reads hit the local L2.
    const int bid = blockIdx.x;
    const int cpx = gridDim.x >> 3;
    const int wb  = (bid & 7) * cpx + (bid >> 3);
    const int bz  = wb >> 7;          // image
    const int row = wb & 127;         // row

    const size_t imgbase = (size_t)bz * C_DIM * HW;
    const int c0   = wv * CPW;
    const int col0 = 2 * l;

    const float* pfe = fe + imgbase + (size_t)c0 * HW + row * W_DIM + col0;
    const float* pfu = fu + imgbase + (size_t)c0 * HW + row * W_DIM + col0;
    const bool has_u = (row > 0), has_d = (row < H_DIM - 1);

    float d0[9], d1[9];
#pragma unroll
    for (int k = 0; k < 9; ++k) { d0[k] = 0.f; d1[k] = 0.f; }
    float fe2a = 0.f, fe2b = 0.f;
    float s2[3][2] = {{0.f,0.f},{0.f,0.f},{0.f,0.f}};

    // ---------------- phase 1: dots + norms ----------------
#pragma unroll
    for (int j = 0; j < CPW; ++j) {
        const size_t off = (size_t)j * HW;
        const float2 f  = *(const float2*)(pfe + off);
        const float2 vm = *(const float2*)(pfu + off);
        const float2 vu = has_u ? *(const float2*)(pfu + off - W_DIM) : make_float2(0.f, 0.f);
        const float2 vd = has_d ? *(const float2*)(pfu + off + W_DIM) : make_float2(0.f, 0.f);

        fe2a += f.x * f.x; fe2b += f.y * f.y;
        s2[0][0] += vu.x * vu.x; s2[0][1] += vu.y * vu.y;
        s2[1][0] += vm.x * vm.x; s2[1][1] += vm.y * vm.y;
        s2[2][0] += vd.x * vd.x; s2[2][1] += vd.y * vd.y;

        const float2 vr[3] = { vu, vm, vd };
#pragma unroll
        for (int r = 0; r < 3; ++r) {
            const float2 v = vr[r];
            float lft = __shfl_up(v.y, 1);   lft = (l == 0)  ? 0.f : lft;   // col 2l-1
            float rgt = __shfl_down(v.x, 1); rgt = (l == 63) ? 0.f : rgt;   // col 2l+2
            d0[3*r+0] += f.x * lft;  d0[3*r+1] += f.x * v.x;  d0[3*r+2] += f.x * v.y;
            d1[3*r+0] += f.y * v.x;  d1[3*r+1] += f.y * v.y;  d1[3*r+2] += f.y * rgt;
        }
    }

    // ---------------- cross-wave reduce (2-step, 4 slots) ----------------
    if (wv < NSLOT) {
#pragma unroll
        for (int k = 0; k < 9; ++k) { part[wv][col0][k] = d0[k]; part[wv][col0+1][k] = d1[k]; }
        part[wv][col0][9] = fe2a; part[wv][col0+1][9] = fe2b;
#pragma unroll
        for (int r = 0; r < 3; ++r) { part2[wv][r][col0] = s2[r][0]; part2[wv][r][col0+1] = s2[r][1]; }
    }
    __syncthreads();
    if (wv >= NSLOT) {
        const int s = wv - NSLOT;
#pragma unroll
        for (int k = 0; k < 9; ++k) { part[s][col0][k] += d0[k]; part[s][col0+1][k] += d1[k]; }
        part[s][col0][9] += fe2a; part[s][col0+1][9] += fe2b;
#pragma unroll
        for (int r = 0; r < 3; ++r) { part2[s][r][col0] += s2[r][0]; part2[s][r][col0+1] += s2[r][1]; }
    }
    __syncthreads();

    // reciprocal clamped norms for the 3 staged rows
    if (tid < 3 * W_DIM) {
        const int r = tid >> 7, c = tid & 127;
        const float s = part2[0][r][c] + part2[1][r][c] + part2[2][r][c] + part2[3][r][c];
        n2r[r][c] = 1.f / fmaxf(sqrtf(s), EPS_N);
    }
    __syncthreads();

    // ---------------- softmax (one thread per pixel) ----------------
    if (tid < W_DIM) {
        const int px = tid;
        float dv[10];
#pragma unroll
        for (int v = 0; v < 10; ++v)
            dv[v] = part[0][px][v] + part[1][px][v] + part[2][px][v] + part[3][px][v];
        const float rfe = 1.f / fmaxf(sqrtf(dv[9]), EPS_N);
        float cs[9];
        float mx = -1e30f;
#pragma unroll
        for (int k = 0; k < 9; ++k) {
            const int di = k / 3, dj = k % 3;
            const int nr = row + di - 1, nc = px + dj - 1;
            const bool ok = (nr >= 0 && nr < H_DIM && nc >= 0 && nc < W_DIM);
            const float cv = ok ? dv[k] * rfe * n2r[di][nc] : 0.f;
            cs[k] = cv;
            mx = fmaxf(mx, cv);
        }
        float sum = 0.f;
#pragma unroll
        for (int k = 0; k < 9; ++k) { cs[k] = __expf(cs[k] - mx); sum += cs[k]; }
        const float is = 1.f / sum;
#pragma unroll
        for (int k = 0; k < 9; ++k) wl[px][k] = cs[k] * is;
    }
    __syncthreads();

    // ---------------- phase 2: weighted aggregation + residual ----------------
    float wa[9], wb_[9];
#pragma unroll
    for (int k = 0; k < 9; ++k) { wa[k] = wl[col0][k]; wb_[k] = wl[col0+1][k]; }

    float* pout = out + imgbase + (size_t)c0 * HW + row * W_DIM + col0;
#pragma unroll
    for (int j = 0; j < CPW; ++j) {
        const size_t off = (size_t)j * HW;
        const float2 f  = *(const float2*)(pfe + off);
        const float2 vm = *(const float2*)(pfu + off);
        const float2 vu = has_u ? *(const float2*)(pfu + off - W_DIM) : make_float2(0.f, 0.f);
        const float2 vd = has_d ? *(const float2*)(pfu + off + W_DIM) : make_float2(0.f, 0.f);

        float a0 = f.x, a1 = f.y;
        const float2 vr[3] = { vu, vm, vd };
#pragma unroll
        for (int r = 0; r < 3; ++r) {
            const float2 v = vr[r];
            float lft = __shfl_up(v.y, 1);   lft = (l == 0)  ? 0.f : lft;
            float rgt = __shfl_down(v.x, 1); rgt = (l == 63) ? 0.f : rgt;
            a0 += wa[3*r+0] * lft + wa[3*r+1] * v.x + wa[3*r+2] * v.y;
            a1 += wb_[3*r+0] * v.x + wb_[3*r+1] * v.y + wb_[3*r+2] * rgt;
        }
        float2 o; o.x = a0; o.y = a1;
        *(float2*)(pout + off) = o;
    }
}

extern "C" void kernel_launch(void* const* d_in, const int* in_sizes, int n_in,
                              void* d_out, int out_size, void* d_ws, size_t ws_size,
                              hipStream_t stream) {
    const float* fe = (const float*)d_in[0];   // fe_lv
    const float* fu = (const float*)d_in[1];   // fused_features
    float* out = (float*)d_out;
    const int B = in_sizes[0] / (C_DIM * HW);
    dim3 grid(B * H_DIM);                      // one block per image row (512 for B=4)
    asfr_fused2<<<grid, NT, 0, stream>>>(fe, fu, out);
}